// Round 14
// baseline (32.062 us; speedup 1.0000x reference)
//
#include <hip/hip_runtime.h>

#define NS 131072
#define D 16
#define R 32
#define O 10
#define KTOT 544          // R*D (affine) + R (bias block)
#define EPSF 1e-8f

typedef float v2     __attribute__((ext_vector_type(2)));
typedef float f32x4  __attribute__((ext_vector_type(4)));
typedef short bf16x8 __attribute__((ext_vector_type(8)));

// f32 -> bf16 bits, round-nearest-even (prep only)
static __device__ __forceinline__ short bf(float f) {
    union { float f; unsigned u; } v; v.f = f;
    unsigned r = (v.u + 0x7fffu + ((v.u >> 16) & 1u)) >> 16;
    return (short)r;
}

// packed f32x2 -> bf16x2 in one HW instr
static __device__ __forceinline__ unsigned cvtpk(float lo, float hi) {
    unsigned r;
    asm("v_cvt_pk_bf16_f32 %0, %1, %2" : "=v"(r) : "v"(lo), "v"(hi));
    return r;
}

// prep: nw=-1/(2s^2), nm1=c/s^2, nc0[r]=sum_d w c^2, Ct[o][k] bf16 (16 x 544)
__global__ void anfis_prep(const float* __restrict__ sigmas,
                           const float* __restrict__ centers,
                           const float* __restrict__ coeffs,
                           float* __restrict__ nw,
                           float* __restrict__ nm1,
                           float* __restrict__ nc0,
                           unsigned short* __restrict__ Ct) {
    int i = blockIdx.x * blockDim.x + threadIdx.x;
    if (i < R * D) {
        float s = sigmas[i], c = centers[i];
        float w = -0.5f / (s * s);
        nw[i]  = w;
        nm1[i] = -2.0f * w * c;
    }
    if (i < R) {
        float acc = 0.f;
        for (int d = 0; d < D; ++d) {
            float s = sigmas[i * D + d], c = centers[i * D + d];
            acc += (-0.5f / (s * s)) * c * c;
        }
        nc0[i] = acc;
    }
    if (i < 16 * KTOT) {
        int o = i / KTOT, k = i % KTOT;
        float v = 0.f;
        if (o < O) {
            if (k < R * D) { int r = k >> 4, d = k & 15; v = coeffs[(r * (D + 1) + d) * O + o]; }
            else           { int r = k - R * D;          v = coeffs[(r * (D + 1) + D) * O + o]; }
        }
        Ct[i] = (unsigned short)bf(v);
    }
}

// R11 structure x 2 TILES/BLOCK: grid 1024 = exactly 4 blocks/CU x 256 CU
// (whole grid co-resident, zero churn). Both tiles' X prefetched up front;
// the 5 MFMA phases interleave two independent LDS chains (tile0's
// write->lgkm->read->MFMA hidden under tile1's build and vice versa);
// B-fragment stream shared between tiles. Separate LDS halves -> no WAR,
// single barrier. Epilogue: wave 0 -> tile0, wave 1 -> tile1.
__global__ __launch_bounds__(256, 4) void anfis_main(
    const float* __restrict__ X,
    const float* __restrict__ nw,
    const float* __restrict__ nm1,
    const float* __restrict__ nc0,
    const unsigned short* __restrict__ Ct,
    float* __restrict__ out)
{
    const int tid  = threadIdx.x;
    const int lane = tid & 63;
    const int w    = __builtin_amdgcn_readfirstlane(tid >> 6);
    const int blk0 = blockIdx.x * 128;

    // per-tile, per-wave 4352B region: Z (64 x 4 x 16B), then C-partials
    // overlaid column-major red[o*69 + row].
    __shared__ char  lbuf[2][4 * 4352];
    __shared__ float sbuf[2][256];

    // ---- load x for BOTH tiles (issued together, overlapped) ----
    v2 x2[2][8];
    #pragma unroll
    for (int t = 0; t < 2; ++t) {
        const float4* xp = reinterpret_cast<const float4*>(X + (size_t)(blk0 + t * 64 + lane) * D);
        #pragma unroll
        for (int i = 0; i < 4; ++i) {
            float4 v = xp[i];
            x2[t][2*i]   = v2{v.x, v.y};
            x2[t][2*i+1] = v2{v.z, v.w};
        }
    }

    // ---- B prefetch for phase 0 (shared by both tiles) ----
    const int o = lane & 15, g = lane >> 4;
    const unsigned short* cbase = Ct + o * KTOT + g * 8;
    bf16x8 bnext = *reinterpret_cast<const bf16x8*>(cbase + w * 128);

    // ---- membership for both tiles: e = sum_d (w x^2 + m1 x) + c0 ----
    float s[2][8];
    #pragma unroll
    for (int t = 0; t < 2; ++t) {
        const int r0 = w * 8;
        float psum = 0.f;
        #pragma unroll
        for (int j = 0; j < 8; ++j) {
            const int r = r0 + j;
            const v2* W2 = reinterpret_cast<const v2*>(nw  + r * D);
            const v2* M2 = reinterpret_cast<const v2*>(nm1 + r * D);
            v2 e2 = v2{0.f, 0.f};
            #pragma unroll
            for (int i = 0; i < 8; ++i) {
                e2 = __builtin_elementwise_fma(x2[t][i] * x2[t][i], W2[i], e2);
                e2 = __builtin_elementwise_fma(x2[t][i],            M2[i], e2);
            }
            s[t][j] = __expf(e2.x + e2.y + nc0[r]);
            psum += s[t][j];
        }
        sbuf[t][tid] = psum;   // consumed only after the single barrier
    }

    f32x4 acc[2][4];
    #pragma unroll
    for (int t = 0; t < 2; ++t)
        #pragma unroll
        for (int rt = 0; rt < 4; ++rt) acc[t][rt] = f32x4{0.f, 0.f, 0.f, 0.f};

    #define ZPHYS(row, chunk) ((((row) * 4 + (chunk)) ^ (((row) >> 1) & 7)))

    // ---- 5 phases, two interleaved tile-chains ----
    #pragma unroll
    for (int p = 0; p < 5; ++p) {
        bf16x8 bcur = bnext;
        if (p < 4) {
            const int k0n = (p + 1 < 4) ? (w * 128 + (p + 1) * 32) : (R * D);
            bnext = *reinterpret_cast<const bf16x8*>(cbase + k0n);
        }
        // build + write Z for both tiles (tile1's build covers tile0's lgkm)
        #pragma unroll
        for (int t = 0; t < 2; ++t) {
            bf16x8* zw = reinterpret_cast<bf16x8*>(lbuf[t] + w * 4352);
            if (p < 4) {
                #pragma unroll
                for (int j = 0; j < 4; ++j) {
                    const float nq = s[t][2 * p + (j >> 1)];
                    union { unsigned u[4]; bf16x8 v; } ch;
                    #pragma unroll
                    for (int m = 0; m < 4; ++m) {
                        v2 tt = x2[t][(j & 1) * 4 + m] * nq;
                        ch.u[m] = cvtpk(tt.x, tt.y);
                    }
                    zw[ZPHYS(lane, j)] = ch.v;
                }
            } else {
                #pragma unroll
                for (int j = 0; j < 4; ++j) {
                    union { unsigned u[4]; bf16x8 v; } ch;
                    #pragma unroll
                    for (int m = 0; m < 4; ++m)
                        ch.u[m] = (j == w) ? cvtpk(s[t][2 * m], s[t][2 * m + 1]) : 0u;
                    zw[ZPHYS(lane, j)] = ch.v;
                }
            }
        }
        // read + MFMA for both tiles (independent acc chains: 2x MFMA ILP)
        #pragma unroll
        for (int t = 0; t < 2; ++t) {
            bf16x8* zw = reinterpret_cast<bf16x8*>(lbuf[t] + w * 4352);
            #pragma unroll
            for (int rt = 0; rt < 4; ++rt) {
                bf16x8 af = zw[ZPHYS((lane & 15) + rt * 16, g)];
                acc[t][rt] = __builtin_amdgcn_mfma_f32_16x16x32_bf16(af, bcur, acc[t][rt], 0, 0, 0);
            }
        }
    }

    // ---- stash C-partials, transposed: red[o*69 + row] ----
    if (o < O) {
        #pragma unroll
        for (int t = 0; t < 2; ++t) {
            float* rw = reinterpret_cast<float*>(lbuf[t] + w * 4352);
            #pragma unroll
            for (int rt = 0; rt < 4; ++rt)
                *reinterpret_cast<f32x4*>(rw + o * 69 + rt * 16 + g * 4) = acc[t][rt];
        }
    }
    __syncthreads();   // the ONLY barrier

    // ---- epilogue: wave 0 -> tile0, wave 1 -> tile1; lane = sample ----
    if (w < 2) {
        const char* lb = lbuf[w];
        const float tot = sbuf[w][lane] + sbuf[w][lane + 64]
                        + sbuf[w][lane + 128] + sbuf[w][lane + 192];
        const float inv = __builtin_amdgcn_rcpf(tot + EPSF);
        float a[O];
        #pragma unroll
        for (int oo = 0; oo < O; ++oo) {
            a[oo] = (reinterpret_cast<const float*>(lb +     0)[oo * 69 + lane]
                   + reinterpret_cast<const float*>(lb +  4352)[oo * 69 + lane]
                   + reinterpret_cast<const float*>(lb +  8704)[oo * 69 + lane]
                   + reinterpret_cast<const float*>(lb + 13056)[oo * 69 + lane]) * inv;
        }
        float m = a[0];
        #pragma unroll
        for (int oo = 1; oo < O; ++oo) m = fmaxf(m, a[oo]);
        float e_[O]; float se = 0.f;
        #pragma unroll
        for (int oo = 0; oo < O; ++oo) { e_[oo] = __expf(a[oo] - m); se += e_[oo]; }
        const float rs = __builtin_amdgcn_rcpf(se);
        float2* op = reinterpret_cast<float2*>(out + (size_t)(blk0 + w * 64 + lane) * O);
        #pragma unroll
        for (int pp = 0; pp < 5; ++pp) op[pp] = make_float2(e_[2*pp] * rs, e_[2*pp+1] * rs);
    }
}

extern "C" void kernel_launch(void* const* d_in, const int* in_sizes, int n_in,
                              void* d_out, int out_size, void* d_ws, size_t ws_size,
                              hipStream_t stream) {
    const float* X       = (const float*)d_in[0];
    const float* centers = (const float*)d_in[1];
    const float* sigmas  = (const float*)d_in[2];
    const float* coeffs  = (const float*)d_in[3];
    float* out = (float*)d_out;

    float* nw  = (float*)d_ws;                                   // 512 f32 @ 0
    float* nm1 = (float*)((char*)d_ws + 2048);                   // 512 f32
    float* nc0 = (float*)((char*)d_ws + 4096);                   // 32 f32
    unsigned short* Ct = (unsigned short*)((char*)d_ws + 4224);  // 16*544 bf16

    anfis_prep<<<(16 * KTOT + 255) / 256, 256, 0, stream>>>(sigmas, centers, coeffs,
                                                            nw, nm1, nc0, Ct);
    anfis_main<<<NS / 128, 256, 0, stream>>>(X, nw, nm1, nc0, Ct, out);
}

// Round 15
// 21.553 us; speedup vs baseline: 1.4876x; 1.4876x over previous
//
#include <hip/hip_runtime.h>

#define NS 131072
#define D 16
#define R 32
#define O 10
#define KTOT 544          // R*D (affine) + R (bias block)
#define EPSF 1e-8f

typedef float v2     __attribute__((ext_vector_type(2)));
typedef float f32x4  __attribute__((ext_vector_type(4)));
typedef short bf16x8 __attribute__((ext_vector_type(8)));

// f32 -> bf16 bits, round-nearest-even (prep only)
static __device__ __forceinline__ short bf(float f) {
    union { float f; unsigned u; } v; v.f = f;
    unsigned r = (v.u + 0x7fffu + ((v.u >> 16) & 1u)) >> 16;
    return (short)r;
}

// packed f32x2 -> bf16x2 in one HW instr
static __device__ __forceinline__ unsigned cvtpk(float lo, float hi) {
    unsigned r;
    asm("v_cvt_pk_bf16_f32 %0, %1, %2" : "=v"(r) : "v"(lo), "v"(hi));
    return r;
}

// prep: nw=-1/(2s^2), nm1=c/s^2, nc0[r]=sum_d w c^2, Ct[o][k] bf16 (16 x 544)
__global__ void anfis_prep(const float* __restrict__ sigmas,
                           const float* __restrict__ centers,
                           const float* __restrict__ coeffs,
                           float* __restrict__ nw,
                           float* __restrict__ nm1,
                           float* __restrict__ nc0,
                           unsigned short* __restrict__ Ct) {
    int i = blockIdx.x * blockDim.x + threadIdx.x;
    if (i < R * D) {
        float s = sigmas[i], c = centers[i];
        float w = -0.5f / (s * s);
        nw[i]  = w;
        nm1[i] = -2.0f * w * c;
    }
    if (i < R) {
        float acc = 0.f;
        for (int d = 0; d < D; ++d) {
            float s = sigmas[i * D + d], c = centers[i * D + d];
            acc += (-0.5f / (s * s)) * c * c;
        }
        nc0[i] = acc;
    }
    if (i < 16 * KTOT) {
        int o = i / KTOT, k = i % KTOT;
        float v = 0.f;
        if (o < O) {
            if (k < R * D) { int r = k >> 4, d = k & 15; v = coeffs[(r * (D + 1) + d) * O + o]; }
            else           { int r = k - R * D;          v = coeffs[(r * (D + 1) + D) * O + o]; }
        }
        Ct[i] = (unsigned short)bf(v);
    }
}

// R9 FINAL STRUCTURE (best: 21.56us). 4 waves x 64 samples; wave w owns
// rules [8w,8w+8); membership on VALU (expanded form, wave-uniform s_load
// params); consequent via 5 MFMA phases on Z = nrm*x staged in wave-private
// swizzled LDS; C-partials overlay Z; wave-0 epilogue.
// launch_bounds(256,4): 128-VGPR budget vs ~70 live -> spill-free (the one
// property every regression since R4 violated).
__global__ __launch_bounds__(256, 4) void anfis_main(
    const float* __restrict__ X,
    const float* __restrict__ nw,
    const float* __restrict__ nm1,
    const float* __restrict__ nc0,
    const unsigned short* __restrict__ Ct,
    float* __restrict__ out)
{
    const int tid  = threadIdx.x;
    const int lane = tid & 63;
    const int w    = __builtin_amdgcn_readfirstlane(tid >> 6);
    const int n    = blockIdx.x * 64 + lane;

    // per-wave 4352B region: Z (64 x 4 x 16B) then C-partials (64 x 17 f32) overlaid
    __shared__ char  lbuf[4 * 4352];
    __shared__ float sbuf[256];
    bf16x8* zw = reinterpret_cast<bf16x8*>(lbuf + w * 4352);
    float*  rw = reinterpret_cast<float*> (lbuf + w * 4352);

    // ---- load x ----
    v2 x2[8];
    {
        const float4* xp = reinterpret_cast<const float4*>(X + (size_t)n * D);
        #pragma unroll
        for (int i = 0; i < 4; ++i) {
            float4 v = xp[i];
            x2[2*i]   = v2{v.x, v.y};
            x2[2*i+1] = v2{v.z, v.w};
        }
    }

    // ---- B prefetch for phase 0 ----
    const int o = lane & 15, g = lane >> 4;
    const unsigned short* cbase = Ct + o * KTOT + g * 8;
    bf16x8 bnext = *reinterpret_cast<const bf16x8*>(cbase + w * 128);

    // ---- membership: e = sum_d (w x^2 + m1 x) + c0 ----
    float s[8];
    {
        const int r0 = w * 8;
        float psum = 0.f;
        #pragma unroll
        for (int j = 0; j < 8; ++j) {
            const int r = r0 + j;
            const v2* W2 = reinterpret_cast<const v2*>(nw  + r * D);
            const v2* M2 = reinterpret_cast<const v2*>(nm1 + r * D);
            v2 e2 = v2{0.f, 0.f};
            #pragma unroll
            for (int i = 0; i < 8; ++i) {
                e2 = __builtin_elementwise_fma(x2[i] * x2[i], W2[i], e2);
                e2 = __builtin_elementwise_fma(x2[i],         M2[i], e2);
            }
            s[j] = __expf(e2.x + e2.y + nc0[r]);
            psum += s[j];
        }
        sbuf[tid] = psum;
    }
    __syncthreads();

    // ---- normalize strengths IN PLACE ----
    {
        float tot = sbuf[lane] + sbuf[lane + 64] + sbuf[lane + 128] + sbuf[lane + 192];
        const float inv = __builtin_amdgcn_rcpf(tot + EPSF);
        #pragma unroll
        for (int j = 0; j < 8; ++j) s[j] *= inv;
    }

    f32x4 acc[4];
    #pragma unroll
    for (int rt = 0; rt < 4; ++rt) acc[rt] = f32x4{0.f, 0.f, 0.f, 0.f};

    #define ZPHYS(row, chunk) ((((row) * 4 + (chunk)) ^ (((row) >> 1) & 7)))

    // ---- 5 phases: p<4 => 2 rules (K=32); p==4 => bias block ----
    #pragma unroll
    for (int p = 0; p < 5; ++p) {
        bf16x8 bcur = bnext;
        if (p < 4) {
            const int k0n = (p + 1 < 4) ? (w * 128 + (p + 1) * 32) : (R * D);
            bnext = *reinterpret_cast<const bf16x8*>(cbase + k0n);
        }
        if (p < 4) {
            // z[k=q*16+d] = s[2p+q]*x[d]; chunk j: rule q=j>>1, d-range (j&1)*8..+8
            #pragma unroll
            for (int j = 0; j < 4; ++j) {
                const float nq = s[2 * p + (j >> 1)];
                union { unsigned u[4]; bf16x8 v; } ch;
                #pragma unroll
                for (int m = 0; m < 4; ++m) {
                    v2 t = x2[(j & 1) * 4 + m] * nq;
                    ch.u[m] = cvtpk(t.x, t.y);
                }
                zw[ZPHYS(lane, j)] = ch.v;
            }
        } else {
            // bias: k-slot g*8+e <-> rule g*8+e; this wave supplies chunk w only
            #pragma unroll
            for (int j = 0; j < 4; ++j) {
                union { unsigned u[4]; bf16x8 v; } ch;
                #pragma unroll
                for (int m = 0; m < 4; ++m)
                    ch.u[m] = (j == w) ? cvtpk(s[2 * m], s[2 * m + 1]) : 0u;
                zw[ZPHYS(lane, j)] = ch.v;
            }
        }
        #pragma unroll
        for (int rt = 0; rt < 4; ++rt) {
            bf16x8 af = zw[ZPHYS((lane & 15) + rt * 16, g)];
            acc[rt] = __builtin_amdgcn_mfma_f32_16x16x32_bf16(af, bcur, acc[rt], 0, 0, 0);
        }
    }

    // ---- stash C-partials over the Z region (wave-private) ----
    #pragma unroll
    for (int rt = 0; rt < 4; ++rt) {
        #pragma unroll
        for (int j = 0; j < 4; ++j)
            rw[(rt * 16 + g * 4 + j) * 17 + o] = acc[rt][j];
    }
    __syncthreads();

    // ---- epilogue: wave 0, lane = sample ----
    if (tid < 64) {
        float a[O];
        #pragma unroll
        for (int oo = 0; oo < O; ++oo) {
            a[oo] = reinterpret_cast<const float*>(lbuf +    0)[tid * 17 + oo]
                  + reinterpret_cast<const float*>(lbuf + 4352)[tid * 17 + oo]
                  + reinterpret_cast<const float*>(lbuf + 8704)[tid * 17 + oo]
                  + reinterpret_cast<const float*>(lbuf +13056)[tid * 17 + oo];
        }
        float m = a[0];
        #pragma unroll
        for (int oo = 1; oo < O; ++oo) m = fmaxf(m, a[oo]);
        float e_[O]; float se = 0.f;
        #pragma unroll
        for (int oo = 0; oo < O; ++oo) { e_[oo] = __expf(a[oo] - m); se += e_[oo]; }
        const float rs = __builtin_amdgcn_rcpf(se);
        float2* op = reinterpret_cast<float2*>(out + (size_t)(blockIdx.x * 64 + tid) * O);
        #pragma unroll
        for (int pp = 0; pp < 5; ++pp) op[pp] = make_float2(e_[2*pp] * rs, e_[2*pp+1] * rs);
    }
}

extern "C" void kernel_launch(void* const* d_in, const int* in_sizes, int n_in,
                              void* d_out, int out_size, void* d_ws, size_t ws_size,
                              hipStream_t stream) {
    const float* X       = (const float*)d_in[0];
    const float* centers = (const float*)d_in[1];
    const float* sigmas  = (const float*)d_in[2];
    const float* coeffs  = (const float*)d_in[3];
    float* out = (float*)d_out;

    float* nw  = (float*)d_ws;                                   // 512 f32 @ 0
    float* nm1 = (float*)((char*)d_ws + 2048);                   // 512 f32
    float* nc0 = (float*)((char*)d_ws + 4096);                   // 32 f32
    unsigned short* Ct = (unsigned short*)((char*)d_ws + 4224);  // 16*544 bf16

    anfis_prep<<<(16 * KTOT + 255) / 256, 256, 0, stream>>>(sigmas, centers, coeffs,
                                                            nw, nm1, nc0, Ct);
    anfis_main<<<NS / 64, 256, 0, stream>>>(X, nw, nm1, nc0, Ct, out);
}